// Round 1
// baseline (122.620 us; speedup 1.0000x reference)
//
#include <hip/hip_runtime.h>
#include <math.h>

#define B_ 8
#define L_ 200
#define H_ 128
#define NH_ 2
#define HD_ 64
#define LP_ 256   // padded L (pad region never zeroed; OOB contributions discarded)
#define TV_ 32    // time vocab
#define RQ_ 8     // rows per qkv block

// ---------------------------------------------------------------- fused QKV
// grid (B*L/RQ_, 3), 128 threads; m = 0:Q, 1:K(transposed), 2:V
__global__ __launch_bounds__(128)
void qkv_kernel(const float* __restrict__ X,
                const float* __restrict__ Wq, const float* __restrict__ bq,
                const float* __restrict__ Wk, const float* __restrict__ bk,
                const float* __restrict__ Wv, const float* __restrict__ bv,
                const float* __restrict__ kpt, const float* __restrict__ vpt,
                float* __restrict__ Q, float* __restrict__ Kt, float* __restrict__ Vp){
    const int r0 = blockIdx.x * RQ_;
    const int m  = blockIdx.y;
    const int j  = threadIdx.x;
    __shared__ __align__(16) float xs[RQ_][H_];
    #pragma unroll
    for (int r = 0; r < RQ_; ++r) xs[r][j] = X[(r0 + r) * H_ + j];
    __syncthreads();
    const float* W = (m == 0) ? Wq : ((m == 1) ? Wk : Wv);
    float acc[RQ_];
    #pragma unroll
    for (int r = 0; r < RQ_; ++r) acc[r] = 0.f;
    // float4 xs broadcasts: 8 ds_read_b128 per 4 K-steps (was 32 ds_read_b32)
    #pragma unroll 2
    for (int i4 = 0; i4 < H_ / 4; ++i4) {
        const int i = i4 * 4;
        const float w0 = W[(i + 0) * H_ + j];
        const float w1 = W[(i + 1) * H_ + j];
        const float w2 = W[(i + 2) * H_ + j];
        const float w3 = W[(i + 3) * H_ + j];
        #pragma unroll
        for (int r = 0; r < RQ_; ++r) {
            const float4 xv = ((const float4*)xs[r])[i4];
            acc[r] += xv.x * w0 + xv.y * w1 + xv.z * w2 + xv.w * w3;
        }
    }
    const int h = j >> 6, d = j & 63;
    if (m == 0) {
        const float bj = bq[j];
        #pragma unroll
        for (int r = 0; r < RQ_; ++r) Q[(r0 + r) * H_ + j] = acc[r] + bj;
    } else if (m == 1) {
        const float bj = bk[j];
        #pragma unroll
        for (int r = 0; r < RQ_; ++r) {
            const int row = r0 + r, b = row / L_, l = row % L_;
            Kt[((b * NH_ + h) * HD_ + d) * LP_ + l] = acc[r] + bj + kpt[l * H_ + j];
        }
    } else {
        const float bj = bv[j];
        #pragma unroll
        for (int r = 0; r < RQ_; ++r) {
            const int row = r0 + r, b = row / L_, l = row % L_;
            Vp[((b * NH_ + h) * L_ + l) * HD_ + d] = acc[r] + bj + vpt[l * H_ + j];
        }
    }
}

// ------------------------------------------- fused attention + out-proj + LN
// grid = B * (L/4) = 400 blocks of 512 threads (8 waves).
// wave w: head h = w&1, q-row qr = w>>1 -> q = q0 + qr (one q per wave).
__global__ __launch_bounds__(512)
void attn_out_kernel(const float* __restrict__ Q, const float* __restrict__ Kt,
                     const float* __restrict__ Vp, const int* __restrict__ tseq,
                     const float* __restrict__ mask,
                     const float* __restrict__ ktt, const float* __restrict__ vtt,
                     const float* __restrict__ Wd, const float* __restrict__ bd,
                     const float* __restrict__ X, const float* __restrict__ g,
                     const float* __restrict__ bb, float* __restrict__ out){
    const int b  = blockIdx.x / (L_ / 4);
    const int q0 = (blockIdx.x % (L_ / 4)) * 4;
    const int w  = threadIdx.x >> 6, lane = threadIdx.x & 63;
    const int h  = w & 1, qr = w >> 1;
    const int q  = q0 + qr;
    const int bh = b * NH_ + h;

    __shared__ float ktt_s[TV_][H_ + 1];   // +1 pad: scalar reads conflict-free
    __shared__ float vtt_s[TV_][H_ + 1];
    __shared__ __align__(16) float qs   [4][2][HD_];
    __shared__ float qkt_s[8][TV_];
    __shared__ float ss_s [8][TV_];
    __shared__ __align__(16) float ps_s [8][LP_];
    __shared__ __align__(16) float ctx_s[4][H_];
    __shared__ float redA[8], redB[8];

    // coalesced table staging (16.5 KB x2)
    for (int t = threadIdx.x; t < TV_ * H_; t += 512) {
        ktt_s[t >> 7][t & 127] = ktt[t];
        vtt_s[t >> 7][t & 127] = vtt[t];
    }
    qs[qr][h][lane] = Q[(b * L_ + q) * H_ + h * HD_ + lane];   // wave-private q
    if (lane < TV_) ss_s[w][lane] = 0.f;
    __syncthreads();

    // qkt[bkt] = dot(q, ktt[bkt, head slice]); 2 lanes per bucket
    {
        const int bkt = lane >> 1, half = lane & 1;
        const float* kr = &ktt_s[bkt][h * HD_ + half * 32];
        const float* qv = &qs[qr][h][half * 32];
        float a = 0.f;
        #pragma unroll
        for (int d2 = 0; d2 < 32; ++d2) a += qv[d2] * kr[d2];
        a += __shfl_xor(a, 1);
        if (half == 0) qkt_s[w][bkt] = a;   // same-wave LDS, ordered
    }

    // ---- phase A: lane handles k = 4*lane .. 4*lane+3
    const float4* kt4 = (const float4*)(Kt + (size_t)bh * HD_ * LP_);
    const float4* qv4 = (const float4*)qs[qr][h];
    float4 s4 = make_float4(0.f, 0.f, 0.f, 0.f);
    #pragma unroll 4
    for (int d4 = 0; d4 < HD_ / 4; ++d4) {
        const float4 qq = qv4[d4];
        const float4 k0 = kt4[(d4 * 4 + 0) * (LP_ / 4) + lane];
        const float4 k1 = kt4[(d4 * 4 + 1) * (LP_ / 4) + lane];
        const float4 k2 = kt4[(d4 * 4 + 2) * (LP_ / 4) + lane];
        const float4 k3 = kt4[(d4 * 4 + 3) * (LP_ / 4) + lane];
        s4.x += qq.x * k0.x + qq.y * k1.x + qq.z * k2.x + qq.w * k3.x;
        s4.y += qq.x * k0.y + qq.y * k1.y + qq.z * k2.y + qq.w * k3.y;
        s4.z += qq.x * k0.z + qq.y * k1.z + qq.z * k2.z + qq.w * k3.z;
        s4.w += qq.x * k0.w + qq.y * k1.w + qq.z * k2.w + qq.w * k3.w;
    }
    float sv[4] = {s4.x, s4.y, s4.z, s4.w};
    const int k0i = lane * 4;
    float mx = -INFINITY;
    if (k0i < L_) {  // lanes 0..49; rows 800B-aligned -> float4/int4 ok
        const float4 m4 = ((const float4*)(mask + ((size_t)(b * L_ + q)) * L_))[lane];
        const int4   t4 = ((const int4*)(tseq + b * L_))[lane];
        const int    tq = tseq[b * L_ + q];
        const float mv[4] = {m4.x, m4.y, m4.z, m4.w};
        const int   tk[4] = {t4.x, t4.y, t4.z, t4.w};
        #pragma unroll
        for (int jj = 0; jj < 4; ++jj) {
            int dt = tq - tk[jj]; if (dt < 0) dt = -dt;
            int ib = (int)log1pf((float)dt); if (ib > TV_ - 1) ib = TV_ - 1;
            const float s = (sv[jj] + qkt_s[w][ib]) * 0.125f + mv[jj];
            sv[jj] = s;
            atomicAdd(&ss_s[w][ib], s);     // pre-softmax bucket sums
            if (s > mx) mx = s;
        }
    } else {
        sv[0] = sv[1] = sv[2] = sv[3] = -INFINITY;  // Kt pad garbage discarded
    }
    #pragma unroll
    for (int off = 32; off; off >>= 1) { const float o = __shfl_xor(mx, off); if (o > mx) mx = o; }
    float sum = 0.f, ev[4];
    #pragma unroll
    for (int jj = 0; jj < 4; ++jj) {
        const float e = (k0i + jj < L_) ? __expf(sv[jj] - mx) : 0.f;
        ev[jj] = e; sum += e;
    }
    #pragma unroll
    for (int off = 32; off; off >>= 1) sum += __shfl_xor(sum, off);
    ((float4*)ps_s[w])[lane] = make_float4(ev[0], ev[1], ev[2], ev[3]);
    const float inv = 1.f / sum;

    // ---- phase B (PV): lane = (kk = k-group, d4 = d-quad); float4 V loads
    {
        const int kk = lane >> 4, d4 = lane & 15;
        const float4* vp4 = (const float4*)(Vp + (size_t)bh * L_ * HD_);
        float4 c4 = make_float4(0.f, 0.f, 0.f, 0.f);
        #pragma unroll 5
        for (int kb = 0; kb < L_; kb += 4) {
            const float  p  = ps_s[w][kb + kk];               // same-wave LDS, ordered
            const float4 vv = vp4[(kb + kk) * (HD_ / 4) + d4];
            c4.x += p * vv.x; c4.y += p * vv.y; c4.z += p * vv.z; c4.w += p * vv.w;
        }
        // butterfly over kk (lane bits 4,5)
        #pragma unroll
        for (int off = 16; off <= 32; off <<= 1) {
            c4.x += __shfl_xor(c4.x, off);
            c4.y += __shfl_xor(c4.y, off);
            c4.z += __shfl_xor(c4.z, off);
            c4.w += __shfl_xor(c4.w, off);
        }
        if (kk == 0) {
            c4.x *= inv; c4.y *= inv; c4.z *= inv; c4.w *= inv;
            *(float4*)&ctx_s[qr][h * HD_ + d4 * 4] = c4;
        }
    }
    // time-ctx: lane = d (conflict-free 2-way), raw pre-softmax scores
    {
        float tc = 0.f;
        #pragma unroll
        for (int i = 0; i < TV_; ++i) tc += ss_s[w][i] * vtt_s[i][h * HD_ + lane];
        ctx_s[qr][h * HD_ + lane] += tc;   // same-wave LDS after float4 store: ordered
    }
    __syncthreads();

    // ---- out projection + residual + one-pass LayerNorm: 1 row/thread
    const int rr = threadIdx.x >> 7, j = threadIdx.x & 127;
    const float4* cr = (const float4*)ctx_s[rr];
    float acc = 0.f;
    #pragma unroll 8
    for (int i4 = 0; i4 < H_ / 4; ++i4) {
        const float4 xa = cr[i4];
        const int i = i4 * 4;
        acc += xa.x * Wd[(i + 0) * H_ + j];
        acc += xa.y * Wd[(i + 1) * H_ + j];
        acc += xa.z * Wd[(i + 2) * H_ + j];
        acc += xa.w * Wd[(i + 3) * H_ + j];
    }
    const int row = b * L_ + q0 + rr;
    const float x = acc + bd[j] + X[row * H_ + j];
    float s1 = x, s2 = x * x;
    #pragma unroll
    for (int off = 32; off; off >>= 1) { s1 += __shfl_xor(s1, off); s2 += __shfl_xor(s2, off); }
    if (lane == 0) { redA[w] = s1; redB[w] = s2; }
    __syncthreads();
    const float mean = (redA[2 * rr] + redA[2 * rr + 1]) * (1.f / H_);
    const float ex2  = (redB[2 * rr] + redB[2 * rr + 1]) * (1.f / H_);
    const float var  = ex2 - mean * mean;
    out[row * H_ + j] = (x - mean) * rsqrtf(var + 1e-12f) * g[j] + bb[j];
}

// ---------------------------------------------------------------- launch
extern "C" void kernel_launch(void* const* d_in, const int* in_sizes, int n_in,
                              void* d_out, int out_size, void* d_ws, size_t ws_size,
                              hipStream_t stream) {
    const float* X    = (const float*)d_in[0];
    const int*   tseq = (const int*)  d_in[1];
    const float* mask = (const float*)d_in[2];
    const float* Wq = (const float*)d_in[3],  *bq = (const float*)d_in[4];
    const float* Wk = (const float*)d_in[5],  *bk = (const float*)d_in[6];
    const float* Wv = (const float*)d_in[7],  *bv = (const float*)d_in[8];
    const float* Wd = (const float*)d_in[9],  *bd = (const float*)d_in[10];
    const float* g  = (const float*)d_in[11], *bb = (const float*)d_in[12];
    const float* ktt = (const float*)d_in[13], *vtt = (const float*)d_in[14];
    const float* kpt = (const float*)d_in[15], *vpt = (const float*)d_in[16];

    float* ws  = (float*)d_ws;
    float* Q   = ws;                          // B*L*H      = 204800
    float* Kt  = Q   + B_ * L_ * H_;          // B*NH*HD*LP = 262144 (pad unzeroed, by design)
    float* Vp  = Kt  + B_ * NH_ * HD_ * LP_;  // B*L*H      = 204800

    dim3 g1(B_ * L_ / RQ_, 3);
    qkv_kernel<<<g1, 128, 0, stream>>>(X, Wq, bq, Wk, bk, Wv, bv, kpt, vpt, Q, Kt, Vp);
    attn_out_kernel<<<B_ * (L_ / 4), 512, 0, stream>>>(Q, Kt, Vp, tseq, mask, ktt, vtt,
                                                       Wd, bd, X, g, bb, (float*)d_out);
}

// Round 2
// 122.040 us; speedup vs baseline: 1.0048x; 1.0048x over previous
//
#include <hip/hip_runtime.h>
#include <math.h>

#define B_ 8
#define L_ 200
#define H_ 128
#define NH_ 2
#define HD_ 64
#define LP_ 256   // padded L (pad region never zeroed; OOB contributions discarded)
#define TV_ 32    // time vocab
#define RQ_ 4     // rows per qkv block (4 -> 1200 blocks, 2.3 waves/SIMD)

// ---------------------------------------------------------------- fused QKV
// grid (B*L/RQ_, 3), 128 threads; m = 0:Q, 1:K(transposed), 2:V
__global__ __launch_bounds__(128)
void qkv_kernel(const float* __restrict__ X,
                const float* __restrict__ Wq, const float* __restrict__ bq,
                const float* __restrict__ Wk, const float* __restrict__ bk,
                const float* __restrict__ Wv, const float* __restrict__ bv,
                const float* __restrict__ kpt, const float* __restrict__ vpt,
                float* __restrict__ Q, float* __restrict__ Kt, float* __restrict__ Vp){
    const int r0 = blockIdx.x * RQ_;
    const int m  = blockIdx.y;
    const int j  = threadIdx.x;
    __shared__ __align__(16) float xs[RQ_][H_];
    #pragma unroll
    for (int r = 0; r < RQ_; ++r) xs[r][j] = X[(r0 + r) * H_ + j];
    __syncthreads();
    const float* W = (m == 0) ? Wq : ((m == 1) ? Wk : Wv);
    float acc[RQ_];
    #pragma unroll
    for (int r = 0; r < RQ_; ++r) acc[r] = 0.f;
    #pragma unroll 4
    for (int i4 = 0; i4 < H_ / 4; ++i4) {
        const int i = i4 * 4;
        const float w0 = W[(i + 0) * H_ + j];
        const float w1 = W[(i + 1) * H_ + j];
        const float w2 = W[(i + 2) * H_ + j];
        const float w3 = W[(i + 3) * H_ + j];
        #pragma unroll
        for (int r = 0; r < RQ_; ++r) {
            const float4 xv = ((const float4*)xs[r])[i4];
            acc[r] += xv.x * w0 + xv.y * w1 + xv.z * w2 + xv.w * w3;
        }
    }
    const int h = j >> 6, d = j & 63;
    if (m == 0) {
        const float bj = bq[j];
        #pragma unroll
        for (int r = 0; r < RQ_; ++r) Q[(r0 + r) * H_ + j] = acc[r] + bj;
    } else if (m == 1) {
        const float bj = bk[j];
        #pragma unroll
        for (int r = 0; r < RQ_; ++r) {
            const int row = r0 + r, b = row / L_, l = row % L_;
            Kt[((b * NH_ + h) * HD_ + d) * LP_ + l] = acc[r] + bj + kpt[l * H_ + j];
        }
    } else {
        const float bj = bv[j];
        #pragma unroll
        for (int r = 0; r < RQ_; ++r) {
            const int row = r0 + r, b = row / L_, l = row % L_;
            Vp[((b * NH_ + h) * L_ + l) * HD_ + d] = acc[r] + bj + vpt[l * H_ + j];
        }
    }
}

// ------------------------------------------- fused attention + out-proj + LN
// grid = B * (L/2) = 800 blocks of 256 threads (4 waves).
// wave w: head h = w&1, q-row qr = w>>1 in {0,1} -> q = q0 + qr.
// No table staging (ktt/vtt are L2-resident, shared by all blocks).
// All LDS below the out-proj join is wave-private -> no barrier until then.
__global__ __launch_bounds__(256)
void attn_out_kernel(const float* __restrict__ Q, const float* __restrict__ Kt,
                     const float* __restrict__ Vp, const int* __restrict__ tseq,
                     const float* __restrict__ mask,
                     const float* __restrict__ ktt, const float* __restrict__ vtt,
                     const float* __restrict__ Wd, const float* __restrict__ bd,
                     const float* __restrict__ X, const float* __restrict__ g,
                     const float* __restrict__ bb, float* __restrict__ out){
    const int b  = blockIdx.x / (L_ / 2);
    const int q0 = (blockIdx.x % (L_ / 2)) * 2;
    const int w  = threadIdx.x >> 6, lane = threadIdx.x & 63;
    const int h  = w & 1, qr = w >> 1;
    const int q  = q0 + qr;
    const int bh = b * NH_ + h;

    __shared__ __align__(16) float qs   [2][2][HD_];
    __shared__ float qkt_s[4][TV_];
    __shared__ float ss_s [4][TV_];
    __shared__ __align__(16) float ps_s [4][LP_];
    __shared__ __align__(16) float ctx_s[2][H_];
    __shared__ float redA[4], redB[4];

    qs[qr][h][lane] = Q[(b * L_ + q) * H_ + h * HD_ + lane];   // wave-private
    if (lane < TV_) ss_s[w][lane] = 0.f;                       // wave-private

    // qkt[bkt] = dot(q, ktt[bkt, head slice]); 2 lanes per bucket, from L2
    {
        const int bkt = lane >> 1, half = lane & 1;
        const float4* kr4 = (const float4*)(ktt + bkt * H_ + h * HD_ + half * 32);
        const float4* qv4p = (const float4*)(&qs[qr][h][half * 32]);
        float a = 0.f;
        #pragma unroll
        for (int d4 = 0; d4 < 8; ++d4) {
            const float4 kv = kr4[d4];
            const float4 qv = qv4p[d4];
            a += qv.x * kv.x + qv.y * kv.y + qv.z * kv.z + qv.w * kv.w;
        }
        a += __shfl_xor(a, 1);
        if (half == 0) qkt_s[w][bkt] = a;   // same-wave LDS, ordered
    }

    // ---- phase A: lane handles k = 4*lane .. 4*lane+3
    const float4* kt4 = (const float4*)(Kt + (size_t)bh * HD_ * LP_);
    const float4* qv4 = (const float4*)qs[qr][h];
    float4 s4 = make_float4(0.f, 0.f, 0.f, 0.f);
    #pragma unroll 4
    for (int d4 = 0; d4 < HD_ / 4; ++d4) {
        const float4 qq = qv4[d4];
        const float4 k0 = kt4[(d4 * 4 + 0) * (LP_ / 4) + lane];
        const float4 k1 = kt4[(d4 * 4 + 1) * (LP_ / 4) + lane];
        const float4 k2 = kt4[(d4 * 4 + 2) * (LP_ / 4) + lane];
        const float4 k3 = kt4[(d4 * 4 + 3) * (LP_ / 4) + lane];
        s4.x += qq.x * k0.x + qq.y * k1.x + qq.z * k2.x + qq.w * k3.x;
        s4.y += qq.x * k0.y + qq.y * k1.y + qq.z * k2.y + qq.w * k3.y;
        s4.z += qq.x * k0.z + qq.y * k1.z + qq.z * k2.z + qq.w * k3.z;
        s4.w += qq.x * k0.w + qq.y * k1.w + qq.z * k2.w + qq.w * k3.w;
    }
    float sv[4] = {s4.x, s4.y, s4.z, s4.w};
    const int k0i = lane * 4;
    float mx = -INFINITY;
    if (k0i < L_) {  // lanes 0..49; rows 800B-aligned -> float4/int4 ok
        const float4 m4 = ((const float4*)(mask + ((size_t)(b * L_ + q)) * L_))[lane];
        const int4   t4 = ((const int4*)(tseq + b * L_))[lane];
        const int    tq = tseq[b * L_ + q];
        const float mv[4] = {m4.x, m4.y, m4.z, m4.w};
        const int   tk[4] = {t4.x, t4.y, t4.z, t4.w};
        #pragma unroll
        for (int jj = 0; jj < 4; ++jj) {
            int dt = tq - tk[jj]; if (dt < 0) dt = -dt;
            int ib = (int)log1pf((float)dt); if (ib > TV_ - 1) ib = TV_ - 1;
            const float s = (sv[jj] + qkt_s[w][ib]) * 0.125f + mv[jj];
            sv[jj] = s;
            atomicAdd(&ss_s[w][ib], s);     // pre-softmax bucket sums (wave-private)
            if (s > mx) mx = s;
        }
    } else {
        sv[0] = sv[1] = sv[2] = sv[3] = -INFINITY;  // Kt pad garbage discarded
    }
    #pragma unroll
    for (int off = 32; off; off >>= 1) { const float o = __shfl_xor(mx, off); if (o > mx) mx = o; }
    float sum = 0.f, ev[4];
    #pragma unroll
    for (int jj = 0; jj < 4; ++jj) {
        const float e = (k0i + jj < L_) ? __expf(sv[jj] - mx) : 0.f;
        ev[jj] = e; sum += e;
    }
    #pragma unroll
    for (int off = 32; off; off >>= 1) sum += __shfl_xor(sum, off);
    ((float4*)ps_s[w])[lane] = make_float4(ev[0], ev[1], ev[2], ev[3]);
    const float inv = 1.f / sum;

    // ---- phase B (PV): lane = (kk = k-group, d4 = d-quad); float4 V loads
    {
        const int kk = lane >> 4, d4 = lane & 15;
        const float4* vp4 = (const float4*)(Vp + (size_t)bh * L_ * HD_);
        float4 c4 = make_float4(0.f, 0.f, 0.f, 0.f);
        #pragma unroll 5
        for (int kb = 0; kb < L_; kb += 4) {
            const float  p  = ps_s[w][kb + kk];               // same-wave LDS, ordered
            const float4 vv = vp4[(kb + kk) * (HD_ / 4) + d4];
            c4.x += p * vv.x; c4.y += p * vv.y; c4.z += p * vv.z; c4.w += p * vv.w;
        }
        #pragma unroll
        for (int off = 16; off <= 32; off <<= 1) {            // butterfly over kk
            c4.x += __shfl_xor(c4.x, off);
            c4.y += __shfl_xor(c4.y, off);
            c4.z += __shfl_xor(c4.z, off);
            c4.w += __shfl_xor(c4.w, off);
        }
        if (kk == 0) {
            c4.x *= inv; c4.y *= inv; c4.z *= inv; c4.w *= inv;
            *(float4*)&ctx_s[qr][h * HD_ + d4 * 4] = c4;
        }
    }
    // time-ctx: lane = d, vtt straight from L2; raw pre-softmax scores
    {
        float tc = 0.f;
        #pragma unroll 8
        for (int i = 0; i < TV_; ++i) tc += ss_s[w][i] * vtt[i * H_ + h * HD_ + lane];
        ctx_s[qr][h * HD_ + lane] += tc;   // same-wave LDS after float4 store: ordered
    }
    __syncthreads();   // join: out-proj reads full ctx rows across waves

    // ---- out projection + residual + one-pass LayerNorm: 1 row per 128 thr
    const int rr = threadIdx.x >> 7, j = threadIdx.x & 127;
    const float4* cr = (const float4*)ctx_s[rr];
    float acc = 0.f;
    #pragma unroll 8
    for (int i4 = 0; i4 < H_ / 4; ++i4) {
        const float4 xa = cr[i4];
        const int i = i4 * 4;
        acc += xa.x * Wd[(i + 0) * H_ + j];
        acc += xa.y * Wd[(i + 1) * H_ + j];
        acc += xa.z * Wd[(i + 2) * H_ + j];
        acc += xa.w * Wd[(i + 3) * H_ + j];
    }
    const int row = b * L_ + q0 + rr;
    const float x = acc + bd[j] + X[row * H_ + j];
    float s1 = x, s2 = x * x;
    #pragma unroll
    for (int off = 32; off; off >>= 1) { s1 += __shfl_xor(s1, off); s2 += __shfl_xor(s2, off); }
    if (lane == 0) { redA[w] = s1; redB[w] = s2; }
    __syncthreads();
    const float mean = (redA[2 * rr] + redA[2 * rr + 1]) * (1.f / H_);
    const float ex2  = (redB[2 * rr] + redB[2 * rr + 1]) * (1.f / H_);
    const float var  = ex2 - mean * mean;
    out[row * H_ + j] = (x - mean) * rsqrtf(var + 1e-12f) * g[j] + bb[j];
}

// ---------------------------------------------------------------- launch
extern "C" void kernel_launch(void* const* d_in, const int* in_sizes, int n_in,
                              void* d_out, int out_size, void* d_ws, size_t ws_size,
                              hipStream_t stream) {
    const float* X    = (const float*)d_in[0];
    const int*   tseq = (const int*)  d_in[1];
    const float* mask = (const float*)d_in[2];
    const float* Wq = (const float*)d_in[3],  *bq = (const float*)d_in[4];
    const float* Wk = (const float*)d_in[5],  *bk = (const float*)d_in[6];
    const float* Wv = (const float*)d_in[7],  *bv = (const float*)d_in[8];
    const float* Wd = (const float*)d_in[9],  *bd = (const float*)d_in[10];
    const float* g  = (const float*)d_in[11], *bb = (const float*)d_in[12];
    const float* ktt = (const float*)d_in[13], *vtt = (const float*)d_in[14];
    const float* kpt = (const float*)d_in[15], *vpt = (const float*)d_in[16];

    float* ws  = (float*)d_ws;
    float* Q   = ws;                          // B*L*H      = 204800
    float* Kt  = Q   + B_ * L_ * H_;          // B*NH*HD*LP = 262144 (pad unzeroed, by design)
    float* Vp  = Kt  + B_ * NH_ * HD_ * LP_;  // B*L*H      = 204800

    dim3 g1(B_ * L_ / RQ_, 3);
    qkv_kernel<<<g1, 128, 0, stream>>>(X, Wq, bq, Wk, bk, Wv, bv, kpt, vpt, Q, Kt, Vp);
    attn_out_kernel<<<B_ * (L_ / 2), 256, 0, stream>>>(Q, Kt, Vp, tseq, mask, ktt, vtt,
                                                       Wd, bd, X, g, bb, (float*)d_out);
}